// Round 19
// baseline (75.281 us; speedup 1.0000x reference)
//
#include <hip/hip_runtime.h>
#include <stdint.h>

typedef _Float16 half8 __attribute__((ext_vector_type(8)));
typedef __fp16 fp16x2 __attribute__((ext_vector_type(2)));
typedef float f32x4 __attribute__((ext_vector_type(4)));
typedef float f32x2 __attribute__((ext_vector_type(2)));
typedef uint32_t u32x2 __attribute__((ext_vector_type(2)));

#define C_ 8
#define W_ 65536
#define F_ 16
#define OW_ 65473
#define K_ 512
#define TILE 2048            // outputs per block (two 1024 K-slices per wave)
#define XH 2112              // halfs per channel row (2048 + 64 halo)
#define SCP 140              // scratch row stride in floats (560 B)
#define SCW 2240             // scratch bytes per wave = 4 rows * 560

// funnel16(hi, lo) = (hi:lo) >> 16  -> v_alignbit_b32
__device__ __forceinline__ uint32_t funnel16(uint32_t hi, uint32_t lo) {
  return (uint32_t)((((uint64_t)hi << 32) | (uint64_t)lo) >> 16);
}
// pack two f32 -> one dword of 2x f16 (v_cvt_pkrtz_f16_f32)
__device__ __forceinline__ uint32_t pk(float a, float b) {
  union { fp16x2 h; uint32_t u; } cv;
  cv.h = __builtin_amdgcn_cvt_pkrtz(a, b);
  return cv.u;
}
// w LDS swizzle (half-index, mult of 4): XOR chunk idx with bits 6-8
__device__ __forceinline__ uint32_t wswz(uint32_t e) {
  uint32_t ch = e >> 3;
  ch ^= (ch >> 6) & 7u;
  return (ch << 4) | ((e & 7u) << 1);
}
__device__ __forceinline__ f32x4 ldx(const float* p) {
  return *reinterpret_cast<const f32x4*>(p);
}

// K loop: 16 k-steps x 8 MFMA; w frag from swizzled LDS, x window 2x b128.
// Mapping (validated R1-R16): t = t0 + off + r + 8*c15, f = 4*g + q.
__device__ __forceinline__ void kloop(const _Float16* __restrict__ wl,
                                      const _Float16* __restrict__ xb,
                                      f32x4 acc[8], int c15, int g, int off) {
  union Win { half8 h[2]; uint32_t d[8]; };
  #pragma unroll
  for (int s = 0; s < 16; ++s) {
    const uint32_t we = (uint32_t)(c15 * K_ + 32 * s + 8 * g);
    const half8 wf = *reinterpret_cast<const half8*>(
                         reinterpret_cast<const char*>(wl) + wswz(we));
    const int c  = s >> 1;
    const int jb = (s & 1) * 32;
    const int A0 = off + 8 * c15 + jb + 8 * g;   // mult of 8 -> 16B aligned
    Win win;
    win.h[0] = *reinterpret_cast<const half8*>(xb + c * XH + A0);
    win.h[1] = *reinterpret_cast<const half8*>(xb + c * XH + A0 + 8);
    #pragma unroll
    for (int r = 0; r < 8; ++r) {
      union { uint32_t d[4]; half8 h; } fr;
      const int m = r >> 1;
      if ((r & 1) == 0) {
        fr.d[0] = win.d[m];     fr.d[1] = win.d[m + 1];
        fr.d[2] = win.d[m + 2]; fr.d[3] = win.d[m + 3];
      } else {
        fr.d[0] = funnel16(win.d[m + 1], win.d[m]);
        fr.d[1] = funnel16(win.d[m + 2], win.d[m + 1]);
        fr.d[2] = funnel16(win.d[m + 3], win.d[m + 2]);
        fr.d[3] = funnel16(win.d[m + 4], win.d[m + 3]);
      }
      acc[r] = __builtin_amdgcn_mfma_f32_16x16x32_f16(wf, fr.h, acc[r], 0, 0, 0);
    }
  }
}

// Epilogue (R14, proven): per-wave PRIVATE LDS transpose -> line-exact
// stores (f32x2 groups cover whole 64B lines).  No sync needed.
template<bool TAIL>
__device__ __forceinline__ void epi(const f32x4 acc[8], f32x4 bv,
                                    float* __restrict__ outn,
                                    float* __restrict__ scw,
                                    int Tw, int c15, int g) {
  #pragma unroll
  for (int q = 0; q < 4; ++q) {
    const float bias = 8.0f * bv[q];   // reference adds bias C times
    f32x4 lo = { acc[0][q] + bias, acc[1][q] + bias,
                 acc[2][q] + bias, acc[3][q] + bias };
    f32x4 hi = { acc[4][q] + bias, acc[5][q] + bias,
                 acc[6][q] + bias, acc[7][q] + bias };
    *reinterpret_cast<f32x4*>(scw + g * SCP + 8 * c15)     = lo;
    *reinterpret_cast<f32x4*>(scw + g * SCP + 8 * c15 + 4) = hi;
    const int f  = 4 * g + q;
    const int tf = (16 - f) & 15;      // (f*OW_ + Tw + tf) % 16 == 0
    float* row = outn + (size_t)f * OW_ + Tw;
    #pragma unroll
    for (int j = 0; j < 3; ++j) {
      const int t = tf + 2 * c15 + 32 * j;
      f32x2 v = { scw[g * SCP + t], scw[g * SCP + t + 1] };
      if (!TAIL || Tw + t + 2 <= OW_) {
        *reinterpret_cast<f32x2*>(row + t) = v;
      } else {
        if (Tw + t     < OW_) row[t]     = v[0];
        if (Tw + t + 1 < OW_) row[t + 1] = v[1];
      }
    }
    #pragma unroll
    for (int e2 = 0; e2 < 2; ++e2) {
      const int e = c15 + 16 * e2;     // 32 edge floats: [0,tf) u [96+tf,128)
      const int t = (e < tf) ? e : 96 + e;
      if (!TAIL || Tw + t < OW_) row[t] = scw[g * SCP + t];
    }
  }
}

// Block = one 2048-t tile of one n; ONE staging pass, ONE barrier; each wave
// runs K(A) -> epi(A) -> K(B) -> epi(B).  epi(A)'s dense line-exact stores
// drain under K(B); scratch is dedicated so no post-staging sync exists.
template<bool TAILB>
__device__ __forceinline__ void block_job(const float* __restrict__ x,
                                          const float* __restrict__ w,
                                          const float* __restrict__ b,
                                          float* __restrict__ out,
                                          char* smem, int n, int t0) {
  _Float16* wl = reinterpret_cast<_Float16*>(smem);            // 16384 B
  _Float16* xb = reinterpret_cast<_Float16*>(smem + 16384);    // 33792 B

  const int tid  = threadIdx.x;
  const int lane = tid & 63;
  const int wv   = tid >> 6;           // 0..7
  const int c15  = lane & 15;
  const int g    = lane >> 4;
  const int tlw  = wv << 7;

  const float* xn = x + (size_t)n * (C_ * W_);
  float* outn = out + (size_t)n * F_ * OW_;

  // ---- stage w: 8192 f32 -> f16 swizzled (4 f32x4 / thread) ----
  #pragma unroll
  for (int j = 0; j < 4; ++j) {
    int e = (tid + 512 * j) * 4;
    f32x4 v = ldx(w + e);
    u32x2 p; p[0] = pk(v[0], v[1]); p[1] = pk(v[2], v[3]);
    *reinterpret_cast<u32x2*>(reinterpret_cast<char*>(wl) + wswz((uint32_t)e)) = p;
  }
  // ---- stage x: 4224 f32x4 units = 8 ch x 528 (2112 halfs/ch) ----
  #pragma unroll
  for (int j = 0; j < 9; ++j) {
    int u = tid + 512 * j;
    if (j == 8 && u >= 4224) break;    // 9th pass: only 128 threads
    int ch = u / 528;
    int pos = (u - ch * 528) * 4;      // 0..2108
    int gi = t0 + pos;
    f32x4 v;
    if (TAILB) v = (gi < W_) ? ldx(xn + (size_t)ch * W_ + gi) : (f32x4){0.f,0.f,0.f,0.f};
    else       v = ldx(xn + (size_t)ch * W_ + gi);
    u32x2 p; p[0] = pk(v[0], v[1]); p[1] = pk(v[2], v[3]);
    *reinterpret_cast<u32x2*>(reinterpret_cast<char*>(xb) +
                              (size_t)(ch * XH + pos) * 2u) = p;
  }

  const f32x4 bv = *reinterpret_cast<const f32x4*>(b + 4 * g);

  __syncthreads();   // the ONLY barrier (true dependency: staging visible)

  float* scw = reinterpret_cast<float*>(smem + 50176 + (size_t)wv * SCW);

  // ---- slice A (never a tail: max Tw+127 = t0+1023 < OW for all blocks) ----
  f32x4 acc[8];
  #pragma unroll
  for (int r = 0; r < 8; ++r) acc[r] = (f32x4){0.f, 0.f, 0.f, 0.f};
  kloop(wl, xb, acc, c15, g, tlw);
  epi<false>(acc, bv, outn, scw, t0 + tlw, c15, g);   // stores drain under K(B)

  // ---- slice B ----
  #pragma unroll
  for (int r = 0; r < 8; ++r) acc[r] = (f32x4){0.f, 0.f, 0.f, 0.f};
  kloop(wl, xb, acc, c15, g, tlw + 1024);
  epi<TAILB>(acc, bv, outn, scw, t0 + 1024 + tlw, c15, g);
}

__global__ __launch_bounds__(512, 4)
void corr1d(const float* __restrict__ x, const float* __restrict__ w,
            const float* __restrict__ b, float* __restrict__ out) {
  // wl 16384 + xb 33792 + scratch 8*2240 = 68096 B -> 2 blocks/CU
  __shared__ __align__(16) char smem[68096];

  const int n  = blockIdx.x >> 5;      // 32 n
  const int bt = blockIdx.x & 31;      // 32 tiles of 2048 t
  const int t0 = bt << 11;

  if (bt < 31) block_job<false>(x, w, b, out, smem, n, t0);
  else         block_job<true >(x, w, b, out, smem, n, t0);
}

extern "C" void kernel_launch(void* const* d_in, const int* in_sizes, int n_in,
                              void* d_out, int out_size, void* d_ws, size_t ws_size,
                              hipStream_t stream) {
  (void)in_sizes; (void)n_in; (void)out_size; (void)d_ws; (void)ws_size;
  const float* x = (const float*)d_in[0];
  const float* w = (const float*)d_in[1];
  const float* b = (const float*)d_in[2];
  float* out = (float*)d_out;
  corr1d<<<dim3(32 * 32), dim3(512), 0, stream>>>(x, w, b, out);
}

// Round 20
// 50.298 us; speedup vs baseline: 1.4967x; 1.4967x over previous
//
#include <hip/hip_runtime.h>
#include <stdint.h>

typedef _Float16 half8 __attribute__((ext_vector_type(8)));
typedef __fp16 fp16x2 __attribute__((ext_vector_type(2)));
typedef float f32x4 __attribute__((ext_vector_type(4)));
typedef float f32x2 __attribute__((ext_vector_type(2)));
typedef uint32_t u32x2 __attribute__((ext_vector_type(2)));

#define C_ 8
#define W_ 65536
#define F_ 16
#define OW_ 65473
#define K_ 512
#define TILE_T 1024
#define XS 1152              // halfs per channel row in x LDS (1024 + 128 halo)
#define SCP 140              // scratch row stride in floats (560 B, 16B-mult)
#define SCW 2240             // scratch bytes per wave = 4 rows * 560

// funnel16(hi, lo) = (hi:lo) >> 16  -> v_alignbit_b32
__device__ __forceinline__ uint32_t funnel16(uint32_t hi, uint32_t lo) {
  return (uint32_t)((((uint64_t)hi << 32) | (uint64_t)lo) >> 16);
}
// pack two f32 -> one dword of 2x f16 (v_cvt_pkrtz_f16_f32)
__device__ __forceinline__ uint32_t pk(float a, float b) {
  union { fp16x2 h; uint32_t u; } cv;
  cv.h = __builtin_amdgcn_cvt_pkrtz(a, b);
  return cv.u;
}
// w LDS swizzle (half-index, mult of 4): XOR chunk idx with bits 6-8
__device__ __forceinline__ uint32_t wswz(uint32_t e) {
  uint32_t ch = e >> 3;
  ch ^= (ch >> 6) & 7u;
  return (ch << 4) | ((e & 7u) << 1);
}
__device__ __forceinline__ f32x4 ldx(const float* p) {
  return *reinterpret_cast<const f32x4*>(p);
}

// One block = one 1024-t tile of one n.  stage w+x -> ONE barrier -> K-loop
// (16 k-steps x 8 MFMA, sliding-window fragments from two aligned b128 LDS
// reads) -> per-wave PRIVATE LDS transpose epilogue (dedicated scratch, no
// second barrier; waves desynchronize and fast waves' dense line-exact
// stores drain under slow waves' MFMA).
// Mapping (validated R1-R16): t = t0 + tlw + r + 8*c15, f = 4*g + q.
template<bool TAIL>
__device__ __forceinline__ void block_job(const float* __restrict__ x,
                                          const float* __restrict__ w,
                                          const float* __restrict__ b,
                                          float* __restrict__ out,
                                          char* smem, int n, int t0) {
  _Float16* wl = reinterpret_cast<_Float16*>(smem);            // 16384 B
  _Float16* xb = reinterpret_cast<_Float16*>(smem + 16384);    // 18432 B

  const int tid  = threadIdx.x;
  const int lane = tid & 63;
  const int wv   = tid >> 6;           // 0..7
  const int c15  = lane & 15;
  const int g    = lane >> 4;

  const float* xn = x + (size_t)n * (C_ * W_);

  // ---- stage w: 8192 f32 -> f16 swizzled (4 f32x4 per thread) ----
  #pragma unroll
  for (int j = 0; j < 4; ++j) {
    int e = (tid + 512 * j) * 4;
    f32x4 v = ldx(w + e);
    u32x2 p; p[0] = pk(v[0], v[1]); p[1] = pk(v[2], v[3]);
    *reinterpret_cast<u32x2*>(reinterpret_cast<char*>(wl) + wswz((uint32_t)e)) = p;
  }
  // ---- stage x: 2176 f32x4 units = 8 ch x 272 ----
  #pragma unroll
  for (int j = 0; j < 5; ++j) {
    int u = tid + 512 * j;
    if (j == 4 && u >= 2176) break;     // 5th pass: only 128 threads
    int ch = u / 272;
    int pos = (u - ch * 272) * 4;       // 0..1084
    int gi = t0 + pos;
    f32x4 v;
    if (TAIL) v = (gi < W_) ? ldx(xn + (size_t)ch * W_ + gi) : (f32x4){0.f,0.f,0.f,0.f};
    else      v = ldx(xn + (size_t)ch * W_ + gi);
    u32x2 p; p[0] = pk(v[0], v[1]); p[1] = pk(v[2], v[3]);
    *reinterpret_cast<u32x2*>(reinterpret_cast<char*>(xb) + (size_t)(ch * XS + pos) * 2u) = p;
  }

  const f32x4 bv = *reinterpret_cast<const f32x4*>(b + 4 * g);

  __syncthreads();   // the ONLY barrier (true dependency: staging visible)

  const int tlw = wv << 7;             // wave's 128-t slice

  f32x4 acc[8];
  #pragma unroll
  for (int r = 0; r < 8; ++r) acc[r] = (f32x4){0.f, 0.f, 0.f, 0.f};

  union Win { half8 h[2]; uint32_t d[8]; };

  #pragma unroll
  for (int s = 0; s < 16; ++s) {
    const uint32_t we = (uint32_t)(c15 * K_ + 32 * s + 8 * g);
    const half8 wf = *reinterpret_cast<const half8*>(
                         reinterpret_cast<const char*>(wl) + wswz(we));
    const int c  = s >> 1;
    const int jb = (s & 1) * 32;
    const int A0 = tlw + 8 * c15 + jb + 8 * g;   // mult of 8 -> 16B aligned
    Win win;
    win.h[0] = *reinterpret_cast<const half8*>(xb + c * XS + A0);
    win.h[1] = *reinterpret_cast<const half8*>(xb + c * XS + A0 + 8);
    #pragma unroll
    for (int r = 0; r < 8; ++r) {
      union { uint32_t d[4]; half8 h; } fr;
      const int m = r >> 1;
      if ((r & 1) == 0) {
        fr.d[0] = win.d[m];     fr.d[1] = win.d[m + 1];
        fr.d[2] = win.d[m + 2]; fr.d[3] = win.d[m + 3];
      } else {
        fr.d[0] = funnel16(win.d[m + 1], win.d[m]);
        fr.d[1] = funnel16(win.d[m + 2], win.d[m + 1]);
        fr.d[2] = funnel16(win.d[m + 3], win.d[m + 2]);
        fr.d[3] = funnel16(win.d[m + 4], win.d[m + 3]);
      }
      acc[r] = __builtin_amdgcn_mfma_f32_16x16x32_f16(wf, fr.h, acc[r], 0, 0, 0);
    }
  }

  // ---- epilogue: per-wave PRIVATE LDS transpose (no barrier needed) ----
  // For each q: 4 f-rows (f = 4g+q); line-exact reads/stores: groups of
  // f32x2 from 16 lanes cover whole 64B lines (row+tf is line-aligned).
  float* scw = reinterpret_cast<float*>(smem + 34816 + (size_t)wv * SCW);
  float* outn = out + (size_t)n * F_ * OW_;
  const int Tw = t0 + tlw;             // multiple of 128

  #pragma unroll
  for (int q = 0; q < 4; ++q) {
    const float bias = 8.0f * bv[q];   // reference adds bias C times
    f32x4 lo = { acc[0][q] + bias, acc[1][q] + bias,
                 acc[2][q] + bias, acc[3][q] + bias };
    f32x4 hi = { acc[4][q] + bias, acc[5][q] + bias,
                 acc[6][q] + bias, acc[7][q] + bias };
    *reinterpret_cast<f32x4*>(scw + g * SCP + 8 * c15)     = lo;
    *reinterpret_cast<f32x4*>(scw + g * SCP + 8 * c15 + 4) = hi;
    // read roles: row g (4 rows), 16 lanes (c15) per row
    const int f  = 4 * g + q;
    const int tf = (16 - f) & 15;      // (f*OW_ + Tw + tf) % 16 == 0
    float* row = outn + (size_t)f * OW_ + Tw;
    #pragma unroll
    for (int j = 0; j < 3; ++j) {
      const int t = tf + 2 * c15 + 32 * j;
      f32x2 v = { scw[g * SCP + t], scw[g * SCP + t + 1] };
      if (!TAIL || Tw + t + 2 <= OW_) {
        *reinterpret_cast<f32x2*>(row + t) = v;
      } else {
        if (Tw + t     < OW_) row[t]     = v[0];
        if (Tw + t + 1 < OW_) row[t + 1] = v[1];
      }
    }
    #pragma unroll
    for (int e2 = 0; e2 < 2; ++e2) {
      const int e = c15 + 16 * e2;     // 32 edge floats: [0,tf) u [96+tf,128)
      const int t = (e < tf) ? e : 96 + e;
      if (!TAIL || Tw + t < OW_) row[t] = scw[g * SCP + t];
    }
  }
}

__global__ __launch_bounds__(512, 6)
void corr1d(const float* __restrict__ x, const float* __restrict__ w,
            const float* __restrict__ b, float* __restrict__ out) {
  // wl 16384 + xb 18432 + per-wave scratch 8*2240 = 52736 B -> 3 blocks/CU
  __shared__ __align__(16) char smem[52736];

  const int n  = blockIdx.x >> 6;      // 32 n
  const int tt = blockIdx.x & 63;      // 64 tiles of 1024 t
  const int t0 = tt * TILE_T;

  if (tt < 63) block_job<false>(x, w, b, out, smem, n, t0);
  else         block_job<true >(x, w, b, out, smem, n, t0);
}

extern "C" void kernel_launch(void* const* d_in, const int* in_sizes, int n_in,
                              void* d_out, int out_size, void* d_ws, size_t ws_size,
                              hipStream_t stream) {
  (void)in_sizes; (void)n_in; (void)out_size; (void)d_ws; (void)ws_size;
  const float* x = (const float*)d_in[0];
  const float* w = (const float*)d_in[1];
  const float* b = (const float*)d_in[2];
  float* out = (float*)d_out;
  corr1d<<<dim3(32 * 64), dim3(512), 0, stream>>>(x, w, b, out);
}